// Round 2
// baseline (1127.424 us; speedup 1.0000x reference)
//
#include <hip/hip_runtime.h>
#include <stdint.h>

// DiT MoM block, MI355X bf16-MFMA implementation.
// B=16 N=256 D=1152 E=270 TOP_K=27 H=256 MLP_H=4608. All dims divide tiles exactly.

#define B_ 16
#define N_ 256
#define D_ 1152
#define E_ 270
#define KTOP 27
#define MLPH 4608
#define D6 6912

typedef float f32;
typedef unsigned short u16;
typedef unsigned int u32;

typedef __attribute__((ext_vector_type(8))) short bf16x8;
typedef __attribute__((ext_vector_type(4))) float f32x4;

__device__ __forceinline__ u16 f2b(f32 x){
  union{f32 f;u32 u;} v; v.f=x;
  u32 r=v.u+0x7FFFu+((v.u>>16)&1u);
  return (u16)(r>>16);
}
__device__ __forceinline__ u32 f2b2(f32 a,f32 b){ return (u32)f2b(a)|((u32)f2b(b)<<16); }
__device__ __forceinline__ f32 gelu_t(f32 x){
  // 0.5x(1+tanh(sqrt(2/pi)(x+0.044715x^3))) ; tanh via exp
  f32 u=0.7978845608028654f*(x+0.044715f*x*x*x);
  f32 e=__expf(2.0f*u);
  return 0.5f*x*(2.0f-2.0f/(e+1.0f));
}
__device__ __forceinline__ f32x4 mfma16(bf16x8 a,bf16x8 b,f32x4 c){
  return __builtin_amdgcn_mfma_f32_16x16x32_bf16(a,b,c,0,0,0);
}

// ---------------- mod = silu(c) @ adaln_w^T + adaln_b ----------------
__global__ void k_modinit(f32* __restrict__ mod, const f32* __restrict__ adb){
  int i=blockIdx.x*256+threadIdx.x;        // 432*256 = 110592 exact
  mod[i]=adb[i%D6];
}
__global__ void k_adaln(f32* __restrict__ mod, const f32* __restrict__ c, const f32* __restrict__ aw){
  __shared__ f32 scs[B_][128];
  const int tid=threadIdx.x;
  const int d0=blockIdx.y*128;
  for(int i=tid;i<B_*128;i+=256){
    int b=i>>7,d=i&127;
    f32 v=c[b*D_+d0+d];
    scs[b][d]=v/(1.f+__expf(-v));
  }
  __syncthreads();
  const int j=blockIdx.x*256+tid;
  f32 acc[B_];
  #pragma unroll
  for(int b=0;b<B_;b++) acc[b]=0.f;
  const f32* wr=aw+(size_t)j*D_+d0;
  for(int d=0;d<128;d+=4){
    float4 w4=*(const float4*)(wr+d);
    #pragma unroll
    for(int b=0;b<B_;b++)
      acc[b]+=w4.x*scs[b][d]+w4.y*scs[b][d+1]+w4.z*scs[b][d+2]+w4.w*scs[b][d+3];
  }
  #pragma unroll
  for(int b=0;b<B_;b++) atomicAdd(&mod[b*D6+j],acc[b]);
}

// ---------------- per-(b,d) stats over tokens (axis=1 LN + router mean) ----------------
__global__ void k_colstats(f32* __restrict__ mu, f32* __restrict__ rstd,
                           const f32* __restrict__ x, const f32* __restrict__ mod){
  const int d=(blockIdx.x*64+threadIdx.x)*2;   // grid.x=9 covers 1152
  const int b=blockIdx.y;
  const f32* xp=x+(size_t)b*N_*D_+d;
  f32 s1a=0,s1b=0,s2a=0,s2b=0;
  for(int n=0;n<N_;n++){
    float2 v=*(const float2*)(xp+(size_t)n*D_);
    s1a+=v.x; s1b+=v.y; s2a+=v.x*v.x; s2b+=v.y*v.y;
  }
  #pragma unroll
  for(int q=0;q<2;q++){
    f32 s1=q?s1b:s1a, s2=q?s2b:s2a;
    int dd=d+q;
    f32 xb=s1*(1.f/N_);
    f32 vx=s2*(1.f/N_)-xb*xb;
    f32 a=1.f+mod[b*D6+D_+dd];
    f32 m=xb*a+mod[b*D6+dd];
    mu[b*D_+dd]=m;
    rstd[b*D_+dd]=rsqrtf(vx*a*a+1e-5f);
  }
}

// ---------------- z^T (d-major) in bf16: z = (x(1+sc)+sh - mu)*rstd ----------------
__global__ void k_ztrans(u16* __restrict__ zt, const f32* __restrict__ x,
                         const f32* __restrict__ mu, const f32* __restrict__ rstd,
                         const f32* __restrict__ mod){
  __shared__ f32 xs[64][129];
  const int tid=threadIdx.x;
  const int dt0=blockIdx.x*128, n0=blockIdx.y*64, b=blockIdx.z;
  const f32* xp=x+((size_t)b*N_+n0)*D_+dt0;
  for(int s=tid;s<2048;s+=256){
    int n=s>>5, cq=(s&31)*4;
    float4 v=*(const float4*)(xp+(size_t)n*D_+cq);
    xs[n][cq]=v.x; xs[n][cq+1]=v.y; xs[n][cq+2]=v.z; xs[n][cq+3]=v.w;
  }
  __syncthreads();
  for(int s=tid;s<1024;s+=256){
    int d=s>>3, g=s&7;
    int gd=dt0+d;
    f32 a=1.f+mod[b*D6+D_+gd];
    f32 sh=mod[b*D6+gd];
    f32 m=mu[b*D_+gd], rs=rstd[b*D_+gd];
    f32 z[8];
    #pragma unroll
    for(int i=0;i<8;i++) z[i]=(xs[g*8+i][d]*a+sh-m)*rs;
    uint4 o; o.x=f2b2(z[0],z[1]); o.y=f2b2(z[2],z[3]); o.z=f2b2(z[4],z[5]); o.w=f2b2(z[6],z[7]);
    *(uint4*)(zt+((size_t)b*D_+gd)*N_+n0+g*8)=o;
  }
}

// ---------------- router logits (exact fp32) ----------------
__global__ void k_router(f32* __restrict__ logits, const f32* __restrict__ mu, const f32* __restrict__ rw){
  const int e=blockIdx.x, lane=threadIdx.x;
  f32 acc[B_];
  #pragma unroll
  for(int b=0;b<B_;b++) acc[b]=0.f;
  const f32* wr=rw+(size_t)e*D_;
  for(int i=0;i<9;i++){
    const int d=(lane+i*64)*2;
    const float2 w2=*(const float2*)(wr+d);
    #pragma unroll
    for(int b=0;b<B_;b++){
      const float2 m2=*(const float2*)(mu+b*D_+d);
      acc[b]+=w2.x*m2.x+w2.y*m2.y;
    }
  }
  #pragma unroll
  for(int b=0;b<B_;b++){
    f32 v=acc[b];
    #pragma unroll
    for(int off=32;off;off>>=1) v+=__shfl_xor(v,off);
    if(lane==0) logits[b*E_+e]=v;
  }
}

// ---------------- softmax + top-27 + aux loss + weighted fc2 bias ----------------
__global__ void k_topk(int* __restrict__ tki, f32* __restrict__ tkw, f32* __restrict__ bias_n,
                       f32* __restrict__ aux_out, const f32* __restrict__ logits,
                       const f32* __restrict__ b2){
  __shared__ f32 probs[B_][E_];
  __shared__ int top1[B_];
  const int tid=threadIdx.x, b=tid>>6, lane=tid&63;
  f32 p[5];
  f32 mx=-1e30f;
  #pragma unroll
  for(int i=0;i<5;i++){ int e=lane+i*64; p[i]=(e<E_)?logits[b*E_+e]:-1e30f; mx=fmaxf(mx,p[i]); }
  #pragma unroll
  for(int off=32;off;off>>=1) mx=fmaxf(mx,__shfl_xor(mx,off));
  f32 sum=0;
  #pragma unroll
  for(int i=0;i<5;i++){ int e=lane+i*64; if(e<E_){ p[i]=__expf(p[i]-mx); sum+=p[i]; } else p[i]=-1.f; }
  #pragma unroll
  for(int off=32;off;off>>=1) sum+=__shfl_xor(sum,off);
  const f32 inv=1.f/sum;
  #pragma unroll
  for(int i=0;i<5;i++){ int e=lane+i*64; if(e<E_){ p[i]*=inv; probs[b][e]=p[i]; } }
  int sidx[KTOP]; f32 sp[KTOP]; f32 swsum=0;
  for(int k=0;k<KTOP;k++){
    f32 bv=-2.f; int bi=E_;
    #pragma unroll
    for(int i=0;i<5;i++){ int e=lane+i*64; if(p[i]>bv||(p[i]==bv&&e<bi)){bv=p[i];bi=e;} }
    #pragma unroll
    for(int off=32;off;off>>=1){
      f32 ov=__shfl_xor(bv,off); int oi=__shfl_xor(bi,off);
      if(ov>bv||(ov==bv&&oi<bi)){bv=ov;bi=oi;}
    }
    sidx[k]=bi; sp[k]=bv; swsum+=bv;
    #pragma unroll
    for(int i=0;i<5;i++){ int e=lane+i*64; if(e==bi) p[i]=-1.f; }
  }
  if(lane==0){
    top1[b]=sidx[0];
    for(int k=0;k<KTOP;k++){ tki[b*KTOP+k]=sidx[k]; tkw[b*KTOP+k]=sp[k]/swsum; }
  }
  f32 accn[4]={0,0,0,0};
  for(int k=0;k<KTOP;k++){
    const f32* br=b2+(size_t)sidx[k]*N_;
    const f32 w=sp[k]/swsum;
    #pragma unroll
    for(int j=0;j<4;j++) accn[j]+=w*br[lane+j*64];
  }
  #pragma unroll
  for(int j=0;j<4;j++) bias_n[b*N_+lane+j*64]=accn[j];
  __syncthreads();
  if(tid<64){
    f32 s=0;
    for(int pr=tid;pr<256;pr+=64) s+=probs[pr&15][top1[pr>>4]];
    #pragma unroll
    for(int off=32;off;off>>=1) s+=__shfl_xor(s,off);
    if(tid==0) aux_out[0]=s*((f32)E_/(f32)(B_*B_));
  }
}

// ---------------- fp32 -> bf16 weight conversion ----------------
__global__ void k_wconv(u16* __restrict__ dst, const f32* __restrict__ src){
  const size_t i=((size_t)blockIdx.x*256+threadIdx.x)*8;
  float4 a=*(const float4*)(src+i), b4=*(const float4*)(src+i+4);
  uint4 o; o.x=f2b2(a.x,a.y); o.y=f2b2(a.z,a.w); o.z=f2b2(b4.x,b4.y); o.w=f2b2(b4.z,b4.w);
  *(uint4*)(dst+i)=o;
}

// ---------------- fused expert phase ----------------
// grid (9 dtiles, 3 ksplits, 16 b), 512 thr. Per block: loop 9 experts:
//   hacc = W1@Z (256x256x128) ; hlds[d][h] = gelu(hacc+b1)*topk_w (bf16)
//   macc += W2@hlds (weighted sum over experts folded into MFMA C)
// then atomicAdd macc into mom.
__global__ __launch_bounds__(512,2) void k_expert(
  f32* __restrict__ mom, const u16* __restrict__ w1b, const u16* __restrict__ w2b,
  const u16* __restrict__ zt, const int* __restrict__ tki, const f32* __restrict__ tkw,
  const f32* __restrict__ fc1b){
  __shared__ u16 wc[2][256][40];
  __shared__ u16 zc[2][128][40];
  __shared__ u16 hlds[128][264];
  __shared__ f32 b1s[256];
  const int tid=threadIdx.x, lane=tid&63, wave=tid>>6;
  const int dt0=blockIdx.x*128, b=blockIdx.z, k0=blockIdx.y*9;
  const int row0=wave*32, c16=lane&15, r4=((lane>>4)<<2), kof=((lane>>4)<<3);
  const int wr0=tid>>2, wq=tid&3;   // W chunk: 256 rows x 32k, slots row=wr0,wr0+128
  const int zr=tid>>2, zq=tid&3;    // Z chunk: 128 rows x 32k
  f32x4 macc[2][8];
  #pragma unroll
  for(int i=0;i<2;i++)
    #pragma unroll
    for(int j=0;j<8;j++) macc[i][j]=(f32x4){0.f,0.f,0.f,0.f};
  const u16* ztb=zt+((size_t)b*D_+dt0)*N_;
  uint4 rw0,rw1,rz;
  for(int kk=0;kk<9;kk++){
    const int e=tki[b*KTOP+k0+kk];
    const f32 wk=tkw[b*KTOP+k0+kk];
    const u16* W1=w1b+(size_t)e*65536;
    const u16* W2=w2b+(size_t)e*65536;
    if(tid<256) b1s[tid]=fc1b[e*256+tid];
    f32x4 hacc[2][8];
    #pragma unroll
    for(int i=0;i<2;i++)
      #pragma unroll
      for(int j=0;j<8;j++) hacc[i][j]=(f32x4){0.f,0.f,0.f,0.f};
    // GEMM1: h = W1 @ Z
    rw0=*(const uint4*)(W1+(size_t)wr0*256+wq*8);
    rw1=*(const uint4*)(W1+(size_t)(wr0+128)*256+wq*8);
    rz =*(const uint4*)(ztb+(size_t)zr*256+zq*8);
    *(uint4*)&wc[0][wr0][wq*8]=rw0;
    *(uint4*)&wc[0][wr0+128][wq*8]=rw1;
    *(uint4*)&zc[0][zr][zq*8]=rz;
    __syncthreads();
    #pragma unroll 1
    for(int kc=0;kc<8;kc++){
      if(kc<7){
        rw0=*(const uint4*)(W1+(size_t)wr0*256+(kc+1)*32+wq*8);
        rw1=*(const uint4*)(W1+(size_t)(wr0+128)*256+(kc+1)*32+wq*8);
        rz =*(const uint4*)(ztb+(size_t)zr*256+(kc+1)*32+zq*8);
      }
      {
        const int bi=kc&1;
        bf16x8 af0=*(const bf16x8*)&wc[bi][row0+c16][kof];
        bf16x8 af1=*(const bf16x8*)&wc[bi][row0+16+c16][kof];
        #pragma unroll
        for(int ct=0;ct<8;ct++){
          bf16x8 bfr=*(const bf16x8*)&zc[bi][ct*16+c16][kof];
          hacc[0][ct]=mfma16(af0,bfr,hacc[0][ct]);
          hacc[1][ct]=mfma16(af1,bfr,hacc[1][ct]);
        }
      }
      if(kc<7){
        const int bi=(kc+1)&1;
        *(uint4*)&wc[bi][wr0][wq*8]=rw0;
        *(uint4*)&wc[bi][wr0+128][wq*8]=rw1;
        *(uint4*)&zc[bi][zr][zq*8]=rz;
      }
      __syncthreads();
    }
    // epilogue -> hlds (d-major), gelu*topk_w
    #pragma unroll
    for(int rt=0;rt<2;rt++){
      const int hr=row0+rt*16+r4;
      #pragma unroll
      for(int ct=0;ct<8;ct++){
        const int dcol=ct*16+c16;
        f32 v0=gelu_t(hacc[rt][ct][0]+b1s[hr+0])*wk;
        f32 v1=gelu_t(hacc[rt][ct][1]+b1s[hr+1])*wk;
        f32 v2=gelu_t(hacc[rt][ct][2]+b1s[hr+2])*wk;
        f32 v3=gelu_t(hacc[rt][ct][3]+b1s[hr+3])*wk;
        uint2 o; o.x=f2b2(v0,v1); o.y=f2b2(v2,v3);
        *(uint2*)&hlds[dcol][hr]=o;
      }
    }
    // GEMM2: macc += W2 @ hlds
    rw0=*(const uint4*)(W2+(size_t)wr0*256+wq*8);
    rw1=*(const uint4*)(W2+(size_t)(wr0+128)*256+wq*8);
    *(uint4*)&wc[0][wr0][wq*8]=rw0;
    *(uint4*)&wc[0][wr0+128][wq*8]=rw1;
    __syncthreads();
    #pragma unroll 1
    for(int kc=0;kc<8;kc++){
      if(kc<7){
        rw0=*(const uint4*)(W2+(size_t)wr0*256+(kc+1)*32+wq*8);
        rw1=*(const uint4*)(W2+(size_t)(wr0+128)*256+(kc+1)*32+wq*8);
      }
      {
        const int bi=kc&1;
        bf16x8 af0=*(const bf16x8*)&wc[bi][row0+c16][kof];
        bf16x8 af1=*(const bf16x8*)&wc[bi][row0+16+c16][kof];
        #pragma unroll
        for(int ct=0;ct<8;ct++){
          bf16x8 bfr=*(const bf16x8*)&hlds[ct*16+c16][kc*32+kof];
          macc[0][ct]=mfma16(af0,bfr,macc[0][ct]);
          macc[1][ct]=mfma16(af1,bfr,macc[1][ct]);
        }
      }
      if(kc<7){
        const int bi=(kc+1)&1;
        *(uint4*)&wc[bi][wr0][wq*8]=rw0;
        *(uint4*)&wc[bi][wr0+128][wq*8]=rw1;
      }
      __syncthreads();
    }
  }
  f32* mb=mom+(size_t)b*N_*D_+dt0;
  #pragma unroll
  for(int rt=0;rt<2;rt++){
    const int nr=row0+rt*16+r4;
    #pragma unroll
    for(int ct=0;ct<8;ct++){
      const int dc=ct*16+c16;
      #pragma unroll
      for(int j=0;j<4;j++)
        atomicAdd(&mb[(size_t)(nr+j)*D_+dc],macc[rt][ct][j]);
    }
  }
}

// ---------------- mom + weighted fc2 bias -> bf16 ----------------
__global__ void k_momcomb(u16* __restrict__ mb, const f32* __restrict__ mom, const f32* __restrict__ bias_n){
  const size_t i=((size_t)blockIdx.x*256+threadIdx.x)*4;
  const int t=(int)(i/D_);
  float4 a=*(const float4*)(mom+i);
  const f32 bn=bias_n[t];
  uint2 o; o.x=f2b2(a.x+bn,a.y+bn); o.y=f2b2(a.z+bn,a.w+bn);
  *(uint2*)(mb+i)=o;
}

// ---------------- generic 128x128 GEMM C = A(bf16) @ W(fp32,[N][K])^T + epilogue ----------------
// EPI 1: out=y= x + g_mom*(acc+bias)   EPI 2: out=bf16(gelu(acc+bias))   EPI 3: out= y + g_mlp*(acc+bias)
template<int EPI>
__global__ __launch_bounds__(256,2) void k_gemm(
  const u16* __restrict__ A, const f32* __restrict__ Wf, const f32* __restrict__ bias,
  const f32* __restrict__ aux1, const f32* __restrict__ mod,
  f32* __restrict__ outf, u16* __restrict__ outb, const int K, const int ldo){
  __shared__ u16 asb[2][128][72];
  __shared__ u16 wsb[2][128][72];
  const int tid=threadIdx.x, lane=tid&63, wave=tid>>6;
  const int nt0=blockIdx.x*128, mt0=blockIdx.y*128;
  const int row0=wave*32, c16=lane&15, r4=((lane>>4)<<2), kof=((lane>>4)<<3);
  f32x4 acc[2][8];
  #pragma unroll
  for(int i=0;i<2;i++)
    #pragma unroll
    for(int j=0;j<8;j++) acc[i][j]=(f32x4){0.f,0.f,0.f,0.f};
  const int NK=K>>6;
  uint4 ra[4]; float4 rwv[8];
  auto ldA=[&](int kc){
    #pragma unroll
    for(int s=0;s<4;s++){ int slot=tid+s*256; int row=slot>>3,q=slot&7;
      ra[s]=*(const uint4*)(A+(size_t)(mt0+row)*K+(size_t)kc*64+q*8); } };
  auto stA=[&](int bi){
    #pragma unroll
    for(int s=0;s<4;s++){ int slot=tid+s*256; int row=slot>>3,q=slot&7;
      *(uint4*)&asb[bi][row][q*8]=ra[s]; } };
  auto ldW=[&](int kc){
    #pragma unroll
    for(int s=0;s<4;s++){ int slot=tid+s*256; int row=slot>>3,q=slot&7;
      const f32* p=Wf+(size_t)(nt0+row)*K+(size_t)kc*64+q*8;
      rwv[2*s]=*(const float4*)p; rwv[2*s+1]=*(const float4*)(p+4); } };
  auto stW=[&](int bi){
    #pragma unroll
    for(int s=0;s<4;s++){ int slot=tid+s*256; int row=slot>>3,q=slot&7;
      uint4 o; o.x=f2b2(rwv[2*s].x,rwv[2*s].y); o.y=f2b2(rwv[2*s].z,rwv[2*s].w);
      o.z=f2b2(rwv[2*s+1].x,rwv[2*s+1].y); o.w=f2b2(rwv[2*s+1].z,rwv[2*s+1].w);
      *(uint4*)&wsb[bi][row][q*8]=o; } };
  ldA(0); ldW(0); stA(0); stW(0);
  __syncthreads();
  #pragma unroll 1
  for(int kc=0;kc<NK;kc++){
    if(kc+1<NK){ ldA(kc+1); ldW(kc+1); }
    {
      const int bi=kc&1;
      #pragma unroll
      for(int ks=0;ks<2;ks++){
        bf16x8 af0=*(const bf16x8*)&asb[bi][row0+c16][ks*32+kof];
        bf16x8 af1=*(const bf16x8*)&asb[bi][row0+16+c16][ks*32+kof];
        #pragma unroll
        for(int ct=0;ct<8;ct++){
          bf16x8 bfr=*(const bf16x8*)&wsb[bi][ct*16+c16][ks*32+kof];
          acc[0][ct]=mfma16(af0,bfr,acc[0][ct]);
          acc[1][ct]=mfma16(af1,bfr,acc[1][ct]);
        }
      }
    }
    if(kc+1<NK){ stA((kc+1)&1); stW((kc+1)&1); }
    __syncthreads();
  }
  #pragma unroll
  for(int rt=0;rt<2;rt++){
    #pragma unroll
    for(int ct=0;ct<8;ct++){
      const int cc=nt0+ct*16+c16;
      const f32 bv=bias[cc];
      #pragma unroll
      for(int j=0;j<4;j++){
        const int r=mt0+row0+rt*16+r4+j;
        f32 v=acc[rt][ct][j]+bv;
        if constexpr(EPI==1){
          f32 g=mod[(r>>8)*D6+2*D_+cc];
          outf[(size_t)r*ldo+cc]=aux1[(size_t)r*ldo+cc]+g*v;
        } else if constexpr(EPI==2){
          outb[(size_t)r*ldo+cc]=f2b(gelu_t(v));
        } else {
          f32 g=mod[(r>>8)*D6+5*D_+cc];
          outf[(size_t)r*ldo+cc]=aux1[(size_t)r*D_+cc]+g*v;
        }
      }
    }
  }
}

// ---------------- per-token LN stats (eps 1e-6) ----------------
__global__ void k_ln2(f32* __restrict__ st, const f32* __restrict__ y){
  const int t=blockIdx.x, tid=threadIdx.x;
  f32 s1=0,s2=0;
  for(int i=tid;i<D_;i+=128){ f32 v=y[(size_t)t*D_+i]; s1+=v; s2+=v*v; }
  #pragma unroll
  for(int off=32;off;off>>=1){ s1+=__shfl_xor(s1,off); s2+=__shfl_xor(s2,off); }
  __shared__ f32 r1[2],r2[2];
  if((tid&63)==0){ r1[tid>>6]=s1; r2[tid>>6]=s2; }
  __syncthreads();
  if(tid==0){
    f32 a=r1[0]+r1[1], q=r2[0]+r2[1];
    f32 m=a*(1.0f/D_);
    f32 var=q*(1.0f/D_)-m*m;
    st[t*2]=m; st[t*2+1]=rsqrtf(var+1e-6f);
  }
}

__global__ void k_mnorm(u16* __restrict__ mb, const f32* __restrict__ y,
                        const f32* __restrict__ st, const f32* __restrict__ mod){
  const size_t i=((size_t)blockIdx.x*256+threadIdx.x)*4;
  const int t=(int)(i/D_); const int b=t>>8; const int d=(int)(i-(size_t)t*D_);
  float4 v=*(const float4*)(y+i);
  const f32 m=st[t*2], rs=st[t*2+1];
  float4 sc=*(const float4*)(mod+b*D6+4*D_+d);
  float4 sh=*(const float4*)(mod+b*D6+3*D_+d);
  f32 a0=(v.x-m)*rs*(1.f+sc.x)+sh.x;
  f32 a1=(v.y-m)*rs*(1.f+sc.y)+sh.y;
  f32 a2=(v.z-m)*rs*(1.f+sc.z)+sh.z;
  f32 a3=(v.w-m)*rs*(1.f+sc.w)+sh.w;
  uint2 o; o.x=f2b2(a0,a1); o.y=f2b2(a2,a3);
  *(uint2*)(mb+i)=o;
}

extern "C" void kernel_launch(void* const* d_in, const int* in_sizes, int n_in,
                              void* d_out, int out_size, void* d_ws, size_t ws_size,
                              hipStream_t stream){
  const f32* x  =(const f32*)d_in[0];
  const f32* c  =(const f32*)d_in[1];
  const f32* rw =(const f32*)d_in[2];
  const f32* f1w=(const f32*)d_in[3];
  const f32* f1b=(const f32*)d_in[4];
  const f32* f2w=(const f32*)d_in[5];
  const f32* f2b_=(const f32*)d_in[6];
  const f32* opw=(const f32*)d_in[7];
  const f32* opb=(const f32*)d_in[8];
  const f32* adw=(const f32*)d_in[9];
  const f32* adb=(const f32*)d_in[10];
  const f32* m1w=(const f32*)d_in[11];
  const f32* m1b=(const f32*)d_in[12];
  const f32* m2w=(const f32*)d_in[13];
  const f32* m2b=(const f32*)d_in[14];
  f32* out=(f32*)d_out;

  char* wsp=(char*)d_ws; size_t off=0;
  auto alloc=[&](size_t bytes)->void*{ void* p=wsp+off; off=(off+bytes+255)&~(size_t)255; return p; };
  f32* mod   =(f32*)alloc((size_t)B_*D6*4);
  f32* mu    =(f32*)alloc((size_t)B_*D_*4);
  f32* rstd  =(f32*)alloc((size_t)B_*D_*4);
  f32* logits=(f32*)alloc((size_t)B_*E_*4);
  int* tki   =(int*)alloc((size_t)B_*KTOP*4);
  f32* tkw   =(f32*)alloc((size_t)B_*KTOP*4);
  f32* bias_n=(f32*)alloc((size_t)B_*N_*4);
  f32* ln2st =(f32*)alloc((size_t)B_*N_*2*4);
  u16* mom_b =(u16*)alloc((size_t)B_*N_*D_*2);
  u16* zt    =(u16*)alloc((size_t)B_*N_*D_*2);
  u16* w1b   =(u16*)alloc((size_t)E_*65536*2);
  u16* w2b   =(u16*)alloc((size_t)E_*65536*2);
  // region reuse (strictly sequential dependencies):
  f32* mom=out;   // fp32 expert accumulator lives in d_out (dead before EPI1 writes y there)
  f32* y  =out;   // EPI1 output; EPI3 reads y[i] then writes out[i] (same thread, same element)
  u16* m_b=zt;    // zt dead after k_expert
  u16* t_b=w1b;   // w1b/w2b dead after k_expert (37.7MB fits in their 70.8MB)
  f32* aux_out=out+(size_t)B_*N_*D_;

  hipMemsetAsync(mom,0,(size_t)B_*N_*D_*4,stream);
  k_modinit<<<432,256,0,stream>>>(mod,adb);
  k_adaln<<<dim3(27,9),256,0,stream>>>(mod,c,adw);
  k_colstats<<<dim3(9,16),64,0,stream>>>(mu,rstd,x,mod);
  k_ztrans<<<dim3(9,4,16),256,0,stream>>>(zt,x,mu,rstd,mod);
  k_router<<<E_,64,0,stream>>>(logits,mu,rw);
  k_topk<<<1,1024,0,stream>>>(tki,tkw,bias_n,aux_out,logits,f2b_);
  k_wconv<<<8640,256,0,stream>>>(w1b,f1w);
  k_wconv<<<8640,256,0,stream>>>(w2b,f2w);
  k_expert<<<dim3(9,3,16),512,0,stream>>>(mom,w1b,w2b,zt,tki,tkw,f1b);
  k_momcomb<<<4608,256,0,stream>>>(mom_b,mom,bias_n);
  k_gemm<1><<<dim3(9,32),256,0,stream>>>(mom_b,opw,opb,x,mod,y,nullptr,D_,D_);
  k_ln2<<<4096,128,0,stream>>>(ln2st,y);
  k_mnorm<<<4608,256,0,stream>>>(m_b,y,ln2st,mod);
  k_gemm<2><<<dim3(36,32),256,0,stream>>>(m_b,m1w,m1b,nullptr,nullptr,nullptr,t_b,D_,MLPH);
  k_gemm<3><<<dim3(9,32),256,0,stream>>>(t_b,m2w,m2b,y,mod,out,nullptr,MLPH,D_);
}